// Round 1
// baseline (224.170 us; speedup 1.0000x reference)
//
#include <hip/hip_runtime.h>

// GraphDecoder (NRI) — round 10: counted-vmcnt pipeline in edge kernel (T3/T4),
// wave-private W2t staging (3-slot ring, depth-2 prefetch), XCD-aware block
// swizzle, b2 in LDS, setprio around MFMA; outmlp reg-prefetch + raw barriers.
// B=32, N=64, F=128, K=4, H=M=NH=256, E=4032.

#define B_ 32
#define N_ 64
#define F_ 128
#define K_ 4
#define E_ 4032

// ws layout (bytes): total 9,961,472 <= proven 9,994,240
#define WS_W2T 0u
#define WS_R   524288u
#define WS_S   4718592u
#define WS_AGG 8912896u

typedef unsigned short u16;
typedef u16    u16x4  __attribute__((ext_vector_type(4)));
typedef u16    u16x8  __attribute__((ext_vector_type(8)));
typedef __bf16 bf16x8 __attribute__((ext_vector_type(8)));
typedef float  f32x4  __attribute__((ext_vector_type(4)));
typedef float  f32x16 __attribute__((ext_vector_type(16)));

__device__ __forceinline__ u16 f2bf(float f) {
    unsigned u; __builtin_memcpy(&u, &f, 4);
    return (u16)((u + 0x7FFFu + ((u >> 16) & 1u)) >> 16);
}
__device__ __forceinline__ float bf2f(u16 u) {
    unsigned v = ((unsigned)u) << 16;
    float f; __builtin_memcpy(&f, &v, 4); return f;
}
__device__ __forceinline__ void gl_lds16(const u16* g, u16* l) {
    __builtin_amdgcn_global_load_lds(
        (const __attribute__((address_space(1))) void*)g,
        (__attribute__((address_space(3))) void*)l, 16, 0, 0);
}

// raw barrier: drain LDS writes for visibility, keep vmcnt free-running.
#define LBAR() do { \
    asm volatile("s_waitcnt lgkmcnt(0)" ::: "memory"); \
    __builtin_amdgcn_s_barrier(); \
    __builtin_amdgcn_sched_barrier(0); \
} while (0)

// ---------------- fused prep (W2 -> cf bf16 chunks) + R/S tables (unchanged, R8-proven) ----------------
__global__ __launch_bounds__(256) void prep_rs_kernel(
    const float* __restrict__ W2, const float* __restrict__ x,
    const float* __restrict__ W1, const float* __restrict__ b1,
    u16* __restrict__ W2t, u16* __restrict__ R, u16* __restrict__ S)
{
    __shared__ u16 ldsA[64 * 136];
    __shared__ u16 ldsW[32 * 136];
    const int tid = threadIdx.x;

    if (blockIdx.x < 1024) {
        // W2t[chunk=k*8+kc][g=ks2*2+lh][n(256)][e(8)] = W2[k][kk][n]
        unsigned gid = blockIdx.x * 256u + tid;
        unsigned chunk = gid >> 13, r = gid & 8191u;
        unsigned g = r >> 11, n = (r >> 3) & 255u, e = r & 7u;
        unsigned k = chunk >> 3, kc = chunk & 7u, ks2 = g >> 1, lhh = g & 1u;
        unsigned kk = kc * 32u + ks2 * 16u + lhh * 8u + e;
        W2t[gid] = f2bf(W2[(k * 256u + kk) * 256u + n]);
        return;
    }

    const int lane = tid & 63, w = tid >> 6;
    const int quad = lane >> 4, mloc = lane & 15;
    const int bx = blockIdx.x - 1024;
    const int k = bx >> 6, half = (bx >> 5) & 1, b = bx & 31;

    for (int idx = tid; idx < 2048; idx += 256) {
        int row = idx >> 5, c4 = idx & 31;
        f32x4 v = *(const f32x4*)&x[(b * 64 + row) * 128 + c4 * 4];
        u16x4 o;
#pragma unroll
        for (int e = 0; e < 4; ++e) o[e] = f2bf(v[e]);
        *(u16x4*)&ldsA[row * 136 + c4 * 4] = o;
    }
    __syncthreads();

    bf16x8 aF[4];
#pragma unroll
    for (int ks = 0; ks < 4; ++ks)
        aF[ks] = *(const bf16x8*)&ldsA[(w * 16 + mloc) * 136 + quad * 8 + ks * 32];

    u16* dst = half ? S : R;
    for (int c = 0; c < 8; ++c) {
        __syncthreads();
        for (int idx = tid; idx < 4096; idx += 256) {
            int n = idx & 31, f = idx >> 5;
            ldsW[n * 136 + f] = f2bf(W1[(k * 256 + half * 128 + f) * 256 + c * 32 + n]);
        }
        __syncthreads();
#pragma unroll
        for (int nt = 0; nt < 2; ++nt) {
            f32x4 acc = (f32x4){0.f, 0.f, 0.f, 0.f};
            const int boff = (nt * 16 + mloc) * 136 + quad * 8;
#pragma unroll
            for (int ks = 0; ks < 4; ++ks)
                acc = __builtin_amdgcn_mfma_f32_16x16x32_bf16(
                    aF[ks], *(const bf16x8*)&ldsW[boff + ks * 32], acc, 0, 0, 0);
            const int n = c * 32 + nt * 16 + mloc;
            const float bias = half ? 0.f : b1[k * 256 + n];
#pragma unroll
            for (int r = 0; r < 4; ++r) {
                int row = w * 16 + quad * 4 + r;
                dst[(size_t)(k * 2048 + b * 64 + row) * 256 + n] = f2bf(acc[r] + bias);
            }
        }
    }
}

// ---------------- edge kernel: counted-vmcnt pipeline, wave-private W staging ----------------
// Per-iter vmem ledger (per wave, steady state):
//   issue svN (1 dwordx4) + 4 glds (chunk it+2)  -> newest 9 at the wait are
//   [glds(it+1) x4, svN, glds(it+2) x4]; s_waitcnt vmcnt(9) => chunk(it) landed.
//   Compiler's own wait for svN at H-build is vmcnt(4) (counted, not 0).
//   No other vmem in the loop (b2 is in LDS) — keep it that way.
__global__ __launch_bounds__(256, 2) void edge6_kernel(
    const u16* __restrict__ R, const u16* __restrict__ S,
    const float* __restrict__ rel, const u16* __restrict__ W2t,
    const float* __restrict__ b2, u16* __restrict__ aggb)
{
    __shared__ u16   WtS[3][8192];       // W2 chunk ring (cf [g][n][8]); wave w owns n in [w*64, w*64+64)
    __shared__ u16   HS[2][4][128][8];   // H chunk dbuf: [g][row=recv*64+j][8kk]
    __shared__ float Rf[2][4][256];      // receiver R rows, f32
    __shared__ float rtS[2][4][64];      // rel_type [recv][k][j], self=0
    __shared__ float b2S[4][256];        // b2 staged (keeps loop vmem-clean)

    const int tid  = threadIdx.x;
    const int lane = tid & 63;
    const int w    = tid >> 6;           // n-quarter 0..3
    const int l31  = lane & 31;
    const int lh   = lane >> 5;
    // XCD-aware swizzle (bijective: 1024 % 8 == 0): blocks sharing b land on one XCD
    const int bid  = ((blockIdx.x & 7) << 7) | (blockIdx.x >> 3);
    const int b    = bid >> 5;
    const int i0   = (bid & 31) * 2;
    const int brow = tid >> 2;           // H-build row (sender j) 0..63
    const int bc   = tid & 3;            // H-build kk-8-group 0..3

    // stage W chunks 0 and 1: wave-private pieces (each wave stages the columns it reads)
#pragma unroll
    for (int g = 0; g < 4; ++g) {
        gl_lds16(W2t + g * 2048 + w * 512 + lane * 8,        &WtS[0][g * 2048 + w * 512]);
        gl_lds16(W2t + 8192 + g * 2048 + w * 512 + lane * 8, &WtS[1][g * 2048 + w * 512]);
    }
    // b2 -> LDS
    for (int t = tid; t < 1024; t += 256) ((float*)b2S)[t] = b2[t];
    // rtS: self-edge trick (j==i -> 0; else jj = j - (j>i))
    for (int t = tid; t < 512; t += 256) {
        int recv = t >> 8, rem = t & 255, k = rem >> 6, j = rem & 63;
        int i = i0 + recv;
        float v = 0.f;
        if (j != i) {
            int jj = j - (j > i);
            v = rel[((size_t)(b * E_) + i * 63 + jj) * 4 + k];
        }
        rtS[recv][k][j] = v;
    }
    // Rf: unpack both receivers' R rows to f32
    {
        int recv = tid >> 7, k = (tid >> 5) & 3, e8 = tid & 31;
        u16x8 t8 = *(const u16x8*)&R[((size_t)(k * 2048 + b * 64 + i0 + recv)) * 256 + e8 * 8];
#pragma unroll
        for (int e = 0; e < 8; ++e) Rf[recv][k][e8 * 8 + e] = bf2f(t8[e]);
    }
    // S slice for chunk 0 (rows contiguous -> coalesced)
    u16x8 sv = *(const u16x8*)&S[((size_t)(b * 64 + brow)) * 256 + bc * 8];
    __syncthreads();   // one-time full drain (chunks 0,1 + all staging)

    // build H chunk 0
    {
#pragma unroll
        for (int recv = 0; recv < 2; ++recv) {
            const float* rp = &Rf[recv][0][bc * 8];
            f32x4 r0 = *(const f32x4*)rp, r1 = *(const f32x4*)(rp + 4);
            bf16x8 o;
#pragma unroll
            for (int e = 0; e < 4; ++e) {
                o[e]     = (__bf16)fmaxf(r0[e] + bf2f(sv[e]),     0.f);
                o[4 + e] = (__bf16)fmaxf(r1[e] + bf2f(sv[4 + e]), 0.f);
            }
            *(bf16x8*)&HS[0][bc][recv * 64 + brow][0] = o;
        }
    }
    LBAR();

    float amsg[2][2] = {{0.f, 0.f}, {0.f, 0.f}};
    f32x16 acc[4][2];
    int sc = 0;                           // slot of current chunk = it % 3

    for (int it = 0; it < 32; ++it) {
        const int kT = it >> 3, kcT = it & 7;
        if (kcT == 0) {
#pragma unroll
            for (int mt = 0; mt < 4; ++mt)
#pragma unroll
                for (int nt = 0; nt < 2; ++nt) acc[mt][nt] = (f32x16)(0.f);
        }
        // issue next S slice FIRST, then glds (order fixes the vmcnt ledger)
        u16x8 svN;
        if (it < 31) {
            const int kT2 = (it + 1) >> 3, kc2 = (it + 1) & 7;
            svN = *(const u16x8*)&S[((size_t)(kT2 * 2048 + b * 64 + brow)) * 256 + kc2 * 32 + bc * 8];
        }
        if (it < 30) {
            const int s2 = (sc < 1) ? sc + 2 : sc - 1;   // (it+2) % 3
            const u16* src = W2t + (size_t)(it + 2) * 8192;
            u16* dstb = &WtS[s2][0];
#pragma unroll
            for (int g = 0; g < 4; ++g)
                gl_lds16(src + g * 2048 + w * 512 + lane * 8, dstb + g * 2048 + w * 512);
        }
        // counted wait: chunk(it) staged; chunks it+1/it+2 stay in flight
        if (it < 30)       { asm volatile("s_waitcnt vmcnt(9)" ::: "memory"); }
        else if (it == 30) { asm volatile("s_waitcnt vmcnt(5)" ::: "memory"); }
        else               { asm volatile("s_waitcnt vmcnt(0)" ::: "memory"); }
        __builtin_amdgcn_sched_barrier(0);

        // MFMA on current H + W (each wave reads only its own staged W pieces)
        const u16* buf = WtS[sc];
        const u16(*hs)[128][8] = HS[it & 1];
        __builtin_amdgcn_s_setprio(1);
#pragma unroll
        for (int ks2 = 0; ks2 < 2; ++ks2) {
            bf16x8 A[4], Bv[2];
#pragma unroll
            for (int mt = 0; mt < 4; ++mt)
                A[mt] = *(const bf16x8*)&hs[ks2 * 2 + lh][mt * 32 + l31][0];
#pragma unroll
            for (int nt = 0; nt < 2; ++nt)
                Bv[nt] = *(const bf16x8*)&buf[(ks2 * 2 + lh) * 2048 + (w * 64 + nt * 32 + l31) * 8];
#pragma unroll
            for (int mt = 0; mt < 4; ++mt)
#pragma unroll
                for (int nt = 0; nt < 2; ++nt)
                    acc[mt][nt] = __builtin_amdgcn_mfma_f32_32x32x16_bf16(A[mt], Bv[nt], acc[mt][nt], 0, 0, 0);
        }
        __builtin_amdgcn_s_setprio(0);

        // build next H chunk
        if (it < 31) {
            const int kT2 = (it + 1) >> 3, kc2 = (it + 1) & 7;
            const int db = (it + 1) & 1;
#pragma unroll
            for (int recv = 0; recv < 2; ++recv) {
                const float* rp = &Rf[recv][kT2][kc2 * 32 + bc * 8];
                f32x4 r0 = *(const f32x4*)rp, r1 = *(const f32x4*)(rp + 4);
                bf16x8 o;
#pragma unroll
                for (int e = 0; e < 4; ++e) {
                    o[e]     = (__bf16)fmaxf(r0[e] + bf2f(svN[e]),     0.f);
                    o[4 + e] = (__bf16)fmaxf(r1[e] + bf2f(svN[4 + e]), 0.f);
                }
                *(bf16x8*)&HS[db][bc][recv * 64 + brow][0] = o;
            }
        }
        // per-k epilogue: bias + relu + rel_type-weighted row fold (no vmem: b2S/rtS in LDS)
        if (kcT == 7) {
#pragma unroll
            for (int nt = 0; nt < 2; ++nt) {
                const float bias = b2S[kT][w * 64 + nt * 32 + l31];
#pragma unroll
                for (int mt = 0; mt < 4; ++mt) {
                    const int recv = mt >> 1;
                    float s = 0.f;
#pragma unroll
                    for (int rq = 0; rq < 4; ++rq) {
                        f32x4 rt4 = *(const f32x4*)&rtS[recv][kT][(mt & 1) * 32 + rq * 8 + 4 * lh];
#pragma unroll
                        for (int e = 0; e < 4; ++e) {
                            float v = acc[mt][nt][rq * 4 + e] + bias;
                            v = v > 0.f ? v : 0.f;
                            s += rt4[e] * v;
                        }
                    }
                    amsg[recv][nt] += s;
                }
            }
        }
        LBAR();                 // HS handoff only (lgkm drain; vmcnt stays counted)
        sc = (sc < 2) ? sc + 1 : 0;
    }

    // fold lh halves; unique writer per slot
#pragma unroll
    for (int recv = 0; recv < 2; ++recv)
#pragma unroll
        for (int nt = 0; nt < 2; ++nt) {
            float s = amsg[recv][nt] + __shfl_xor(amsg[recv][nt], 32);
            if (lh == 0)
                aggb[(size_t)(b * 64 + i0 + recv) * 256 + w * 64 + nt * 32 + l31] = f2bf(s);
        }
}

// ---------------- output MLP: reg-prefetched weight chunks + raw barriers ----------------
// Issue order per chunk: (1) aF loads, (2) wch store (waits wr(kk) -> counted vmcnt,
// aF stays in flight), (3) prefetch wr(kk+1), LBAR, (4) MFMA (waits aF -> counted,
// wr(kk+1) stays in flight), LBAR. No vmcnt(0) drains anywhere in steady state.
__global__ __launch_bounds__(256) void outmlp3_kernel(
    const float* __restrict__ x, const u16* __restrict__ aggb,
    const float* __restrict__ Wo1, const float* __restrict__ bo1,
    const float* __restrict__ Wo2, const float* __restrict__ bo2,
    const float* __restrict__ Wo3, const float* __restrict__ bo3,
    float* __restrict__ out)
{
    __shared__ u16 wch[4][256][8];   // cf weight chunk [g][n][8kk]
    __shared__ u16 p1S[32 * 264];
    __shared__ u16 p2S[32 * 264];
    const int tid = threadIdx.x, lane = tid & 63, w = tid >> 6;
    const int quad = lane >> 4, mloc = lane & 15;
    const int row0 = blockIdx.x * 32;

    {   // ---- L1: K=384 (12 chunks), N=256, aug=[x|agg] ----
        f32x4 acc[2][4];
#pragma unroll
        for (int mt = 0; mt < 2; ++mt)
#pragma unroll
            for (int nt = 0; nt < 4; ++nt) acc[mt][nt] = (f32x4){0.f, 0.f, 0.f, 0.f};
        float wr[32];
#pragma unroll
        for (int g = 0; g < 4; ++g)
#pragma unroll
            for (int e = 0; e < 8; ++e) wr[g * 8 + e] = Wo1[(g * 8 + e) * 256 + tid];
        for (int kk = 0; kk < 12; ++kk) {
            bf16x8 aF[2];
#pragma unroll
            for (int mt = 0; mt < 2; ++mt) {
                const int row = row0 + mt * 16 + mloc;
                if (kk < 4) {
                    u16x8 t;
#pragma unroll
                    for (int e = 0; e < 8; ++e) t[e] = f2bf(x[row * 128 + kk * 32 + quad * 8 + e]);
                    __builtin_memcpy(&aF[mt], &t, 16);
                } else {
                    aF[mt] = *(const bf16x8*)&aggb[(size_t)row * 256 + (kk - 4) * 32 + quad * 8];
                }
            }
#pragma unroll
            for (int g = 0; g < 4; ++g) {
                u16x8 o;
#pragma unroll
                for (int e = 0; e < 8; ++e) o[e] = f2bf(wr[g * 8 + e]);
                *(u16x8*)&wch[g][tid][0] = o;
            }
            if (kk + 1 < 12) {
#pragma unroll
                for (int g = 0; g < 4; ++g)
#pragma unroll
                    for (int e = 0; e < 8; ++e) wr[g * 8 + e] = Wo1[((kk + 1) * 32 + g * 8 + e) * 256 + tid];
            }
            LBAR();
#pragma unroll
            for (int nt = 0; nt < 4; ++nt) {
                bf16x8 bF = *(const bf16x8*)&wch[quad][w * 64 + nt * 16 + mloc][0];
#pragma unroll
                for (int mt = 0; mt < 2; ++mt)
                    acc[mt][nt] = __builtin_amdgcn_mfma_f32_16x16x32_bf16(aF[mt], bF, acc[mt][nt], 0, 0, 0);
            }
            LBAR();
        }
#pragma unroll
        for (int nt = 0; nt < 4; ++nt) {
            const int n = w * 64 + nt * 16 + mloc;
            const float bias = bo1[n];
#pragma unroll
            for (int mt = 0; mt < 2; ++mt)
#pragma unroll
                for (int r = 0; r < 4; ++r) {
                    float v = acc[mt][nt][r] + bias;
                    p1S[(mt * 16 + quad * 4 + r) * 264 + n] = f2bf(v > 0.f ? v : 0.f);
                }
        }
    }
    LBAR();
    {   // ---- L2: K=256 (8 chunks), N=256 ----
        f32x4 acc[2][4];
#pragma unroll
        for (int mt = 0; mt < 2; ++mt)
#pragma unroll
            for (int nt = 0; nt < 4; ++nt) acc[mt][nt] = (f32x4){0.f, 0.f, 0.f, 0.f};
        float wr[32];
#pragma unroll
        for (int g = 0; g < 4; ++g)
#pragma unroll
            for (int e = 0; e < 8; ++e) wr[g * 8 + e] = Wo2[(g * 8 + e) * 256 + tid];
        for (int kk = 0; kk < 8; ++kk) {
            bf16x8 aF[2];
#pragma unroll
            for (int mt = 0; mt < 2; ++mt)
                aF[mt] = *(const bf16x8*)&p1S[(mt * 16 + mloc) * 264 + kk * 32 + quad * 8];
#pragma unroll
            for (int g = 0; g < 4; ++g) {
                u16x8 o;
#pragma unroll
                for (int e = 0; e < 8; ++e) o[e] = f2bf(wr[g * 8 + e]);
                *(u16x8*)&wch[g][tid][0] = o;
            }
            if (kk + 1 < 8) {
#pragma unroll
                for (int g = 0; g < 4; ++g)
#pragma unroll
                    for (int e = 0; e < 8; ++e) wr[g * 8 + e] = Wo2[((kk + 1) * 32 + g * 8 + e) * 256 + tid];
            }
            LBAR();
#pragma unroll
            for (int nt = 0; nt < 4; ++nt) {
                bf16x8 bF = *(const bf16x8*)&wch[quad][w * 64 + nt * 16 + mloc][0];
#pragma unroll
                for (int mt = 0; mt < 2; ++mt)
                    acc[mt][nt] = __builtin_amdgcn_mfma_f32_16x16x32_bf16(aF[mt], bF, acc[mt][nt], 0, 0, 0);
            }
            LBAR();
        }
#pragma unroll
        for (int nt = 0; nt < 4; ++nt) {
            const int n = w * 64 + nt * 16 + mloc;
            const float bias = bo2[n];
#pragma unroll
            for (int mt = 0; mt < 2; ++mt)
#pragma unroll
                for (int r = 0; r < 4; ++r) {
                    float v = acc[mt][nt][r] + bias;
                    p2S[(mt * 16 + quad * 4 + r) * 264 + n] = f2bf(v > 0.f ? v : 0.f);
                }
        }
    }
    LBAR();
    {   // ---- L3: K=256 (8 chunks), N=128, residual ----
        f32x4 acc[2][2];
#pragma unroll
        for (int mt = 0; mt < 2; ++mt)
#pragma unroll
            for (int nt = 0; nt < 2; ++nt) acc[mt][nt] = (f32x4){0.f, 0.f, 0.f, 0.f};
        const int sn = tid & 127, sh = tid >> 7;
        float wr[16];
#pragma unroll
        for (int g2 = 0; g2 < 2; ++g2)
#pragma unroll
            for (int e = 0; e < 8; ++e) wr[g2 * 8 + e] = Wo3[((sh * 2 + g2) * 8 + e) * 128 + sn];
        for (int kk = 0; kk < 8; ++kk) {
            bf16x8 aF[2];
#pragma unroll
            for (int mt = 0; mt < 2; ++mt)
                aF[mt] = *(const bf16x8*)&p2S[(mt * 16 + mloc) * 264 + kk * 32 + quad * 8];
#pragma unroll
            for (int g2 = 0; g2 < 2; ++g2) {
                const int g = sh * 2 + g2;
                u16x8 o;
#pragma unroll
                for (int e = 0; e < 8; ++e) o[e] = f2bf(wr[g2 * 8 + e]);
                *(u16x8*)&wch[g][sn][0] = o;
            }
            if (kk + 1 < 8) {
#pragma unroll
                for (int g2 = 0; g2 < 2; ++g2)
#pragma unroll
                    for (int e = 0; e < 8; ++e)
                        wr[g2 * 8 + e] = Wo3[((kk + 1) * 32 + (sh * 2 + g2) * 8 + e) * 128 + sn];
            }
            LBAR();
#pragma unroll
            for (int nt = 0; nt < 2; ++nt) {
                bf16x8 bF = *(const bf16x8*)&wch[quad][w * 32 + nt * 16 + mloc][0];
#pragma unroll
                for (int mt = 0; mt < 2; ++mt)
                    acc[mt][nt] = __builtin_amdgcn_mfma_f32_16x16x32_bf16(aF[mt], bF, acc[mt][nt], 0, 0, 0);
            }
            LBAR();
        }
#pragma unroll
        for (int nt = 0; nt < 2; ++nt) {
            const int n = w * 32 + nt * 16 + mloc;
            const float bias = bo3[n];
#pragma unroll
            for (int mt = 0; mt < 2; ++mt)
#pragma unroll
                for (int r = 0; r < 4; ++r) {
                    const int grow = row0 + mt * 16 + quad * 4 + r;
                    out[grow * 128 + n] = x[grow * 128 + n] + acc[mt][nt][r] + bias;
                }
        }
    }
}

extern "C" void kernel_launch(void* const* d_in, const int* in_sizes, int n_in,
                              void* d_out, int out_size, void* d_ws, size_t ws_size,
                              hipStream_t stream) {
    const float* x   = (const float*)d_in[0];
    const float* rel = (const float*)d_in[1];
    const float* W1  = (const float*)d_in[4];
    const float* b1  = (const float*)d_in[5];
    const float* W2  = (const float*)d_in[6];
    const float* b2  = (const float*)d_in[7];
    const float* Wo1 = (const float*)d_in[8];
    const float* bo1 = (const float*)d_in[9];
    const float* Wo2 = (const float*)d_in[10];
    const float* bo2 = (const float*)d_in[11];
    const float* Wo3 = (const float*)d_in[12];
    const float* bo3 = (const float*)d_in[13];
    float* out = (float*)d_out;

    char* ws = (char*)d_ws;
    u16* W2t  = (u16*)(ws + WS_W2T);
    u16* R    = (u16*)(ws + WS_R);
    u16* S    = (u16*)(ws + WS_S);
    u16* aggb = (u16*)(ws + WS_AGG);

    prep_rs_kernel<<<1280, 256, 0, stream>>>(W2, x, W1, b1, W2t, R, S);
    edge6_kernel<<<1024, 256, 0, stream>>>(R, S, rel, W2t, b2, aggb);
    outmlp3_kernel<<<64, 256, 0, stream>>>(x, aggb, Wo1, bo1, Wo2, bo2, Wo3, bo3, out);
}

// Round 2
// 207.324 us; speedup vs baseline: 1.0813x; 1.0813x over previous
//
#include <hip/hip_runtime.h>

// GraphDecoder (NRI) — round 11: edge kernel = proven R9 loop structure
// (dbuf + per-iter __syncthreads, compiler-scheduled) + XCD-aware block
// swizzle ONLY (R10 counter-verified: FETCH 22.4->8.3 MB). The R10
// counted-vmcnt/sched_barrier/setprio pipeline regressed (101->115.7 us,
// m141-style order-pinning) and is reverted. outmlp3 reg-prefetch kept
// (non-edge time 115.9 -> 108.5 us).
// B=32, N=64, F=128, K=4, H=M=NH=256, E=4032.

#define B_ 32
#define N_ 64
#define F_ 128
#define K_ 4
#define E_ 4032

// ws layout (bytes): total 9,961,472 <= proven 9,994,240
#define WS_W2T 0u
#define WS_R   524288u
#define WS_S   4718592u
#define WS_AGG 8912896u

typedef unsigned short u16;
typedef u16    u16x4  __attribute__((ext_vector_type(4)));
typedef u16    u16x8  __attribute__((ext_vector_type(8)));
typedef __bf16 bf16x8 __attribute__((ext_vector_type(8)));
typedef float  f32x4  __attribute__((ext_vector_type(4)));
typedef float  f32x16 __attribute__((ext_vector_type(16)));

__device__ __forceinline__ u16 f2bf(float f) {
    unsigned u; __builtin_memcpy(&u, &f, 4);
    return (u16)((u + 0x7FFFu + ((u >> 16) & 1u)) >> 16);
}
__device__ __forceinline__ float bf2f(u16 u) {
    unsigned v = ((unsigned)u) << 16;
    float f; __builtin_memcpy(&f, &v, 4); return f;
}
__device__ __forceinline__ void gl_lds16(const u16* g, u16* l) {
    __builtin_amdgcn_global_load_lds(
        (const __attribute__((address_space(1))) void*)g,
        (__attribute__((address_space(3))) void*)l, 16, 0, 0);
}

// raw barrier for outmlp (LDS-only handoff; keeps vmem prefetch in flight)
#define LBAR() do { \
    asm volatile("s_waitcnt lgkmcnt(0)" ::: "memory"); \
    __builtin_amdgcn_s_barrier(); \
    __builtin_amdgcn_sched_barrier(0); \
} while (0)

// ---------------- fused prep (W2 -> cf bf16 chunks) + R/S tables (R8-proven) ----------------
__global__ __launch_bounds__(256) void prep_rs_kernel(
    const float* __restrict__ W2, const float* __restrict__ x,
    const float* __restrict__ W1, const float* __restrict__ b1,
    u16* __restrict__ W2t, u16* __restrict__ R, u16* __restrict__ S)
{
    __shared__ u16 ldsA[64 * 136];
    __shared__ u16 ldsW[32 * 136];
    const int tid = threadIdx.x;

    if (blockIdx.x < 1024) {
        // W2t[chunk=k*8+kc][g=ks2*2+lh][n(256)][e(8)] = W2[k][kk][n]
        unsigned gid = blockIdx.x * 256u + tid;
        unsigned chunk = gid >> 13, r = gid & 8191u;
        unsigned g = r >> 11, n = (r >> 3) & 255u, e = r & 7u;
        unsigned k = chunk >> 3, kc = chunk & 7u, ks2 = g >> 1, lhh = g & 1u;
        unsigned kk = kc * 32u + ks2 * 16u + lhh * 8u + e;
        W2t[gid] = f2bf(W2[(k * 256u + kk) * 256u + n]);
        return;
    }

    const int lane = tid & 63, w = tid >> 6;
    const int quad = lane >> 4, mloc = lane & 15;
    const int bx = blockIdx.x - 1024;
    const int k = bx >> 6, half = (bx >> 5) & 1, b = bx & 31;

    for (int idx = tid; idx < 2048; idx += 256) {
        int row = idx >> 5, c4 = idx & 31;
        f32x4 v = *(const f32x4*)&x[(b * 64 + row) * 128 + c4 * 4];
        u16x4 o;
#pragma unroll
        for (int e = 0; e < 4; ++e) o[e] = f2bf(v[e]);
        *(u16x4*)&ldsA[row * 136 + c4 * 4] = o;
    }
    __syncthreads();

    bf16x8 aF[4];
#pragma unroll
    for (int ks = 0; ks < 4; ++ks)
        aF[ks] = *(const bf16x8*)&ldsA[(w * 16 + mloc) * 136 + quad * 8 + ks * 32];

    u16* dst = half ? S : R;
    for (int c = 0; c < 8; ++c) {
        __syncthreads();
        for (int idx = tid; idx < 4096; idx += 256) {
            int n = idx & 31, f = idx >> 5;
            ldsW[n * 136 + f] = f2bf(W1[(k * 256 + half * 128 + f) * 256 + c * 32 + n]);
        }
        __syncthreads();
#pragma unroll
        for (int nt = 0; nt < 2; ++nt) {
            f32x4 acc = (f32x4){0.f, 0.f, 0.f, 0.f};
            const int boff = (nt * 16 + mloc) * 136 + quad * 8;
#pragma unroll
            for (int ks = 0; ks < 4; ++ks)
                acc = __builtin_amdgcn_mfma_f32_16x16x32_bf16(
                    aF[ks], *(const bf16x8*)&ldsW[boff + ks * 32], acc, 0, 0, 0);
            const int n = c * 32 + nt * 16 + mloc;
            const float bias = half ? 0.f : b1[k * 256 + n];
#pragma unroll
            for (int r = 0; r < 4; ++r) {
                int row = w * 16 + quad * 4 + r;
                dst[(size_t)(k * 2048 + b * 64 + row) * 256 + n] = f2bf(acc[r] + bias);
            }
        }
    }
}

// ---------------- edge kernel: R9 structure + XCD swizzle ----------------
__global__ __launch_bounds__(256, 2) void edge7_kernel(
    const u16* __restrict__ R, const u16* __restrict__ S,
    const float* __restrict__ rel, const u16* __restrict__ W2t,
    const float* __restrict__ b2, u16* __restrict__ aggb)
{
    __shared__ u16   WtS[2][8192];       // W2 chunk dbuf (cf [g][n][8])
    __shared__ u16   HS[2][4][128][8];   // H chunk dbuf: [g][row=recv*64+j][8kk]
    __shared__ float Rf[2][4][256];      // receiver R rows, f32
    __shared__ float rtS[2][4][64];      // rel_type [recv][k][j], self=0

    const int tid  = threadIdx.x;
    const int lane = tid & 63;
    const int w    = tid >> 6;           // n-quarter 0..3
    const int l31  = lane & 31;
    const int lh   = lane >> 5;
    // XCD-aware swizzle (bijective: 1024 % 8 == 0): the 32 blocks sharing a
    // batch b land on one XCD -> their shared S/W2t/R slices are L2-resident.
    // R10 counter-verified: FETCH_SIZE 22.4 MB -> 8.3 MB.
    const int bid  = ((blockIdx.x & 7) << 7) | (blockIdx.x >> 3);
    const int b    = bid >> 5;
    const int i0   = (bid & 31) * 2;
    const int brow = tid >> 2;           // H-build row (sender j) 0..63
    const int bc   = tid & 3;            // H-build kk-8-group 0..3

    // glds W chunk 0 (each wave stages its 4KB quarter)
    {
        const u16* src = W2t + w * 2048;
        u16* dst = &WtS[0][w * 2048];
#pragma unroll
        for (int it2 = 0; it2 < 4; ++it2)
            gl_lds16(src + it2 * 512 + lane * 8, dst + it2 * 512);
    }
    // rtS: self-edge trick (j==i -> 0; else jj = j - (j>i))
    for (int t = tid; t < 512; t += 256) {
        int recv = t >> 8, rem = t & 255, k = rem >> 6, j = rem & 63;
        int i = i0 + recv;
        float v = 0.f;
        if (j != i) {
            int jj = j - (j > i);
            v = rel[((size_t)(b * E_) + i * 63 + jj) * 4 + k];
        }
        rtS[recv][k][j] = v;
    }
    // Rf: unpack both receivers' R rows to f32
    {
        int recv = tid >> 7, k = (tid >> 5) & 3, e8 = tid & 31;
        u16x8 t8 = *(const u16x8*)&R[((size_t)(k * 2048 + b * 64 + i0 + recv)) * 256 + e8 * 8];
#pragma unroll
        for (int e = 0; e < 8; ++e) Rf[recv][k][e8 * 8 + e] = bf2f(t8[e]);
    }
    // S slice for chunk 0 (rows contiguous -> coalesced)
    u16x8 sv = *(const u16x8*)&S[((size_t)(b * 64 + brow)) * 256 + bc * 8];
    __syncthreads();

    // build H chunk 0
    {
#pragma unroll
        for (int recv = 0; recv < 2; ++recv) {
            const float* rp = &Rf[recv][0][bc * 8];
            f32x4 r0 = *(const f32x4*)rp, r1 = *(const f32x4*)(rp + 4);
            bf16x8 o;
#pragma unroll
            for (int e = 0; e < 4; ++e) {
                o[e]     = (__bf16)fmaxf(r0[e] + bf2f(sv[e]),     0.f);
                o[4 + e] = (__bf16)fmaxf(r1[e] + bf2f(sv[4 + e]), 0.f);
            }
            *(bf16x8*)&HS[0][bc][recv * 64 + brow][0] = o;
        }
    }
    __syncthreads();

    float amsg[2][2] = {{0.f, 0.f}, {0.f, 0.f}};
    f32x16 acc[4][2];

    for (int it = 0; it < 32; ++it) {
        const int kT = it >> 3, kcT = it & 7;
        if (kcT == 0) {
#pragma unroll
            for (int mt = 0; mt < 4; ++mt)
#pragma unroll
                for (int nt = 0; nt < 2; ++nt) acc[mt][nt] = (f32x16)(0.f);
        }
        // prefetch next W chunk (glds) and next S slice (regs)
        u16x8 svN;
        if (it < 31) {
            const u16* src = W2t + (size_t)(it + 1) * 8192 + w * 2048;
            u16* dst = &WtS[(it + 1) & 1][w * 2048];
#pragma unroll
            for (int it2 = 0; it2 < 4; ++it2)
                gl_lds16(src + it2 * 512 + lane * 8, dst + it2 * 512);
            const int kT2 = (it + 1) >> 3, kc2 = (it + 1) & 7;
            svN = *(const u16x8*)&S[((size_t)(kT2 * 2048 + b * 64 + brow)) * 256 + kc2 * 32 + bc * 8];
        }
        // MFMA on current H + W
        const u16* buf = WtS[it & 1];
        const u16(*hs)[128][8] = HS[it & 1];
#pragma unroll
        for (int ks2 = 0; ks2 < 2; ++ks2) {
            bf16x8 A[4], Bv[2];
#pragma unroll
            for (int mt = 0; mt < 4; ++mt)
                A[mt] = *(const bf16x8*)&hs[ks2 * 2 + lh][mt * 32 + l31][0];
#pragma unroll
            for (int nt = 0; nt < 2; ++nt)
                Bv[nt] = *(const bf16x8*)&buf[(ks2 * 2 + lh) * 2048 + (w * 64 + nt * 32 + l31) * 8];
#pragma unroll
            for (int mt = 0; mt < 4; ++mt)
#pragma unroll
                for (int nt = 0; nt < 2; ++nt)
                    acc[mt][nt] = __builtin_amdgcn_mfma_f32_32x32x16_bf16(A[mt], Bv[nt], acc[mt][nt], 0, 0, 0);
        }
        // build next H chunk
        if (it < 31) {
            const int kT2 = (it + 1) >> 3, kc2 = (it + 1) & 7;
            const int db = (it + 1) & 1;
#pragma unroll
            for (int recv = 0; recv < 2; ++recv) {
                const float* rp = &Rf[recv][kT2][kc2 * 32 + bc * 8];
                f32x4 r0 = *(const f32x4*)rp, r1 = *(const f32x4*)(rp + 4);
                bf16x8 o;
#pragma unroll
                for (int e = 0; e < 4; ++e) {
                    o[e]     = (__bf16)fmaxf(r0[e] + bf2f(svN[e]),     0.f);
                    o[4 + e] = (__bf16)fmaxf(r1[e] + bf2f(svN[4 + e]), 0.f);
                }
                *(bf16x8*)&HS[db][bc][recv * 64 + brow][0] = o;
            }
        }
        // per-k epilogue: bias + relu + rel_type-weighted row fold
        if (kcT == 7) {
#pragma unroll
            for (int nt = 0; nt < 2; ++nt) {
                const float bias = b2[kT * 256 + w * 64 + nt * 32 + l31];
#pragma unroll
                for (int mt = 0; mt < 4; ++mt) {
                    const int recv = mt >> 1;
                    float s = 0.f;
#pragma unroll
                    for (int rq = 0; rq < 4; ++rq) {
                        f32x4 rt4 = *(const f32x4*)&rtS[recv][kT][(mt & 1) * 32 + rq * 8 + 4 * lh];
#pragma unroll
                        for (int e = 0; e < 4; ++e) {
                            float v = acc[mt][nt][rq * 4 + e] + bias;
                            v = v > 0.f ? v : 0.f;
                            s += rt4[e] * v;
                        }
                    }
                    amsg[recv][nt] += s;
                }
            }
        }
        __syncthreads();
    }

    // fold lh halves; unique writer per slot
#pragma unroll
    for (int recv = 0; recv < 2; ++recv)
#pragma unroll
        for (int nt = 0; nt < 2; ++nt) {
            float s = amsg[recv][nt] + __shfl_xor(amsg[recv][nt], 32);
            if (lh == 0)
                aggb[(size_t)(b * 64 + i0 + recv) * 256 + w * 64 + nt * 32 + l31] = f2bf(s);
        }
}

// ---------------- output MLP: reg-prefetched weight chunks + raw barriers ----------------
__global__ __launch_bounds__(256) void outmlp3_kernel(
    const float* __restrict__ x, const u16* __restrict__ aggb,
    const float* __restrict__ Wo1, const float* __restrict__ bo1,
    const float* __restrict__ Wo2, const float* __restrict__ bo2,
    const float* __restrict__ Wo3, const float* __restrict__ bo3,
    float* __restrict__ out)
{
    __shared__ u16 wch[4][256][8];   // cf weight chunk [g][n][8kk]
    __shared__ u16 p1S[32 * 264];
    __shared__ u16 p2S[32 * 264];
    const int tid = threadIdx.x, lane = tid & 63, w = tid >> 6;
    const int quad = lane >> 4, mloc = lane & 15;
    const int row0 = blockIdx.x * 32;

    {   // ---- L1: K=384 (12 chunks), N=256, aug=[x|agg] ----
        f32x4 acc[2][4];
#pragma unroll
        for (int mt = 0; mt < 2; ++mt)
#pragma unroll
            for (int nt = 0; nt < 4; ++nt) acc[mt][nt] = (f32x4){0.f, 0.f, 0.f, 0.f};
        float wr[32];
#pragma unroll
        for (int g = 0; g < 4; ++g)
#pragma unroll
            for (int e = 0; e < 8; ++e) wr[g * 8 + e] = Wo1[(g * 8 + e) * 256 + tid];
        for (int kk = 0; kk < 12; ++kk) {
            bf16x8 aF[2];
#pragma unroll
            for (int mt = 0; mt < 2; ++mt) {
                const int row = row0 + mt * 16 + mloc;
                if (kk < 4) {
                    u16x8 t;
#pragma unroll
                    for (int e = 0; e < 8; ++e) t[e] = f2bf(x[row * 128 + kk * 32 + quad * 8 + e]);
                    __builtin_memcpy(&aF[mt], &t, 16);
                } else {
                    aF[mt] = *(const bf16x8*)&aggb[(size_t)row * 256 + (kk - 4) * 32 + quad * 8];
                }
            }
#pragma unroll
            for (int g = 0; g < 4; ++g) {
                u16x8 o;
#pragma unroll
                for (int e = 0; e < 8; ++e) o[e] = f2bf(wr[g * 8 + e]);
                *(u16x8*)&wch[g][tid][0] = o;
            }
            if (kk + 1 < 12) {
#pragma unroll
                for (int g = 0; g < 4; ++g)
#pragma unroll
                    for (int e = 0; e < 8; ++e) wr[g * 8 + e] = Wo1[((kk + 1) * 32 + g * 8 + e) * 256 + tid];
            }
            LBAR();
#pragma unroll
            for (int nt = 0; nt < 4; ++nt) {
                bf16x8 bF = *(const bf16x8*)&wch[quad][w * 64 + nt * 16 + mloc][0];
#pragma unroll
                for (int mt = 0; mt < 2; ++mt)
                    acc[mt][nt] = __builtin_amdgcn_mfma_f32_16x16x32_bf16(aF[mt], bF, acc[mt][nt], 0, 0, 0);
            }
            LBAR();
        }
#pragma unroll
        for (int nt = 0; nt < 4; ++nt) {
            const int n = w * 64 + nt * 16 + mloc;
            const float bias = bo1[n];
#pragma unroll
            for (int mt = 0; mt < 2; ++mt)
#pragma unroll
                for (int r = 0; r < 4; ++r) {
                    float v = acc[mt][nt][r] + bias;
                    p1S[(mt * 16 + quad * 4 + r) * 264 + n] = f2bf(v > 0.f ? v : 0.f);
                }
        }
    }
    LBAR();
    {   // ---- L2: K=256 (8 chunks), N=256 ----
        f32x4 acc[2][4];
#pragma unroll
        for (int mt = 0; mt < 2; ++mt)
#pragma unroll
            for (int nt = 0; nt < 4; ++nt) acc[mt][nt] = (f32x4){0.f, 0.f, 0.f, 0.f};
        float wr[32];
#pragma unroll
        for (int g = 0; g < 4; ++g)
#pragma unroll
            for (int e = 0; e < 8; ++e) wr[g * 8 + e] = Wo2[(g * 8 + e) * 256 + tid];
        for (int kk = 0; kk < 8; ++kk) {
            bf16x8 aF[2];
#pragma unroll
            for (int mt = 0; mt < 2; ++mt)
                aF[mt] = *(const bf16x8*)&p1S[(mt * 16 + mloc) * 264 + kk * 32 + quad * 8];
#pragma unroll
            for (int g = 0; g < 4; ++g) {
                u16x8 o;
#pragma unroll
                for (int e = 0; e < 8; ++e) o[e] = f2bf(wr[g * 8 + e]);
                *(u16x8*)&wch[g][tid][0] = o;
            }
            if (kk + 1 < 8) {
#pragma unroll
                for (int g = 0; g < 4; ++g)
#pragma unroll
                    for (int e = 0; e < 8; ++e) wr[g * 8 + e] = Wo2[((kk + 1) * 32 + g * 8 + e) * 256 + tid];
            }
            LBAR();
#pragma unroll
            for (int nt = 0; nt < 4; ++nt) {
                bf16x8 bF = *(const bf16x8*)&wch[quad][w * 64 + nt * 16 + mloc][0];
#pragma unroll
                for (int mt = 0; mt < 2; ++mt)
                    acc[mt][nt] = __builtin_amdgcn_mfma_f32_16x16x32_bf16(aF[mt], bF, acc[mt][nt], 0, 0, 0);
            }
            LBAR();
        }
#pragma unroll
        for (int nt = 0; nt < 4; ++nt) {
            const int n = w * 64 + nt * 16 + mloc;
            const float bias = bo2[n];
#pragma unroll
            for (int mt = 0; mt < 2; ++mt)
#pragma unroll
                for (int r = 0; r < 4; ++r) {
                    float v = acc[mt][nt][r] + bias;
                    p2S[(mt * 16 + quad * 4 + r) * 264 + n] = f2bf(v > 0.f ? v : 0.f);
                }
        }
    }
    LBAR();
    {   // ---- L3: K=256 (8 chunks), N=128, residual ----
        f32x4 acc[2][2];
#pragma unroll
        for (int mt = 0; mt < 2; ++mt)
#pragma unroll
            for (int nt = 0; nt < 2; ++nt) acc[mt][nt] = (f32x4){0.f, 0.f, 0.f, 0.f};
        const int sn = tid & 127, sh = tid >> 7;
        float wr[16];
#pragma unroll
        for (int g2 = 0; g2 < 2; ++g2)
#pragma unroll
            for (int e = 0; e < 8; ++e) wr[g2 * 8 + e] = Wo3[((sh * 2 + g2) * 8 + e) * 128 + sn];
        for (int kk = 0; kk < 8; ++kk) {
            bf16x8 aF[2];
#pragma unroll
            for (int mt = 0; mt < 2; ++mt)
                aF[mt] = *(const bf16x8*)&p2S[(mt * 16 + mloc) * 264 + kk * 32 + quad * 8];
#pragma unroll
            for (int g2 = 0; g2 < 2; ++g2) {
                const int g = sh * 2 + g2;
                u16x8 o;
#pragma unroll
                for (int e = 0; e < 8; ++e) o[e] = f2bf(wr[g2 * 8 + e]);
                *(u16x8*)&wch[g][sn][0] = o;
            }
            if (kk + 1 < 8) {
#pragma unroll
                for (int g2 = 0; g2 < 2; ++g2)
#pragma unroll
                    for (int e = 0; e < 8; ++e)
                        wr[g2 * 8 + e] = Wo3[((kk + 1) * 32 + (sh * 2 + g2) * 8 + e) * 128 + sn];
            }
            LBAR();
#pragma unroll
            for (int nt = 0; nt < 2; ++nt) {
                bf16x8 bF = *(const bf16x8*)&wch[quad][w * 32 + nt * 16 + mloc][0];
#pragma unroll
                for (int mt = 0; mt < 2; ++mt)
                    acc[mt][nt] = __builtin_amdgcn_mfma_f32_16x16x32_bf16(aF[mt], bF, acc[mt][nt], 0, 0, 0);
            }
            LBAR();
        }
#pragma unroll
        for (int nt = 0; nt < 2; ++nt) {
            const int n = w * 32 + nt * 16 + mloc;
            const float bias = bo3[n];
#pragma unroll
            for (int mt = 0; mt < 2; ++mt)
#pragma unroll
                for (int r = 0; r < 4; ++r) {
                    const int grow = row0 + mt * 16 + quad * 4 + r;
                    out[grow * 128 + n] = x[grow * 128 + n] + acc[mt][nt][r] + bias;
                }
        }
    }
}

extern "C" void kernel_launch(void* const* d_in, const int* in_sizes, int n_in,
                              void* d_out, int out_size, void* d_ws, size_t ws_size,
                              hipStream_t stream) {
    const float* x   = (const float*)d_in[0];
    const float* rel = (const float*)d_in[1];
    const float* W1  = (const float*)d_in[4];
    const float* b1  = (const float*)d_in[5];
    const float* W2  = (const float*)d_in[6];
    const float* b2  = (const float*)d_in[7];
    const float* Wo1 = (const float*)d_in[8];
    const float* bo1 = (const float*)d_in[9];
    const float* Wo2 = (const float*)d_in[10];
    const float* bo2 = (const float*)d_in[11];
    const float* Wo3 = (const float*)d_in[12];
    const float* bo3 = (const float*)d_in[13];
    float* out = (float*)d_out;

    char* ws = (char*)d_ws;
    u16* W2t  = (u16*)(ws + WS_W2T);
    u16* R    = (u16*)(ws + WS_R);
    u16* S    = (u16*)(ws + WS_S);
    u16* aggb = (u16*)(ws + WS_AGG);

    prep_rs_kernel<<<1280, 256, 0, stream>>>(W2, x, W1, b1, W2t, R, S);
    edge7_kernel<<<1024, 256, 0, stream>>>(R, S, rel, W2t, b2, aggb);
    outmlp3_kernel<<<64, 256, 0, stream>>>(x, aggb, Wo1, bo1, Wo2, bo2, Wo3, bo3, out);
}